// Round 2
// baseline (492.564 us; speedup 1.0000x reference)
//
#include <hip/hip_runtime.h>

// SGConv regression, commuted: out = mean_g( S^K (x @ W) + b )
// N=100000 nodes, E=1600000 edges, F=128, K=3 hops, G=512 graphs.
// Round 1: 8-edges-per-thread ILP in the atomic passes (latency-bound fix).

#define BLK 256
#define EPT 8   // edges per thread in atomic passes

// deg counting: deg[col] += 1 (self-loop folded in later as deg+1)
__global__ void k_deg_edges(const int* __restrict__ col, float* __restrict__ deg, int e) {
    int base = (blockIdx.x * blockDim.x + threadIdx.x) * EPT;
    if (base + EPT <= e) {
        int4 c0 = *(const int4*)(col + base);
        int4 c1 = *(const int4*)(col + base + 4);
        atomicAdd(&deg[c0.x], 1.0f);
        atomicAdd(&deg[c0.y], 1.0f);
        atomicAdd(&deg[c0.z], 1.0f);
        atomicAdd(&deg[c0.w], 1.0f);
        atomicAdd(&deg[c1.x], 1.0f);
        atomicAdd(&deg[c1.y], 1.0f);
        atomicAdd(&deg[c1.z], 1.0f);
        atomicAdd(&deg[c1.w], 1.0f);
    } else {
        for (int i = base; i < e; ++i) atomicAdd(&deg[col[i]], 1.0f);
    }
}

// wave-per-row dot product: y[r] = x[r,:]·W; z[r] = t[r] = rsqrt(deg+1)*y[r]
__global__ void k_y(const float* __restrict__ x, const float* __restrict__ W,
                    const float* __restrict__ deg,
                    float* __restrict__ z, float* __restrict__ t, int n) {
    int wave = blockIdx.x * (BLK / 64) + (threadIdx.x >> 6);
    int lane = threadIdx.x & 63;
    if (wave >= n) return;
    const float2* xr = (const float2*)(x + (size_t)wave * 128);
    const float2* wr = (const float2*)W;
    float2 xv = xr[lane];
    float2 wv = wr[lane];
    float s = xv.x * wv.x + xv.y * wv.y;
    #pragma unroll
    for (int off = 32; off; off >>= 1) s += __shfl_down(s, off);
    if (lane == 0) {
        float zz = rsqrtf(deg[wave] + 1.0f) * s;
        z[wave] = zz;
        t[wave] = zz;
    }
}

// one propagation hop (non-self edges): t[col] += z[row], 8 edges/thread
__global__ void k_edges(const int* __restrict__ row, const int* __restrict__ col,
                        const float* __restrict__ z, float* __restrict__ t, int e) {
    int base = (blockIdx.x * blockDim.x + threadIdx.x) * EPT;
    if (base + EPT <= e) {
        int4 r0 = *(const int4*)(row + base);
        int4 r1 = *(const int4*)(row + base + 4);
        int4 c0 = *(const int4*)(col + base);
        int4 c1 = *(const int4*)(col + base + 4);
        float z0 = z[r0.x];
        float z1 = z[r0.y];
        float z2 = z[r0.z];
        float z3 = z[r0.w];
        float z4 = z[r1.x];
        float z5 = z[r1.y];
        float z6 = z[r1.z];
        float z7 = z[r1.w];
        atomicAdd(&t[c0.x], z0);
        atomicAdd(&t[c0.y], z1);
        atomicAdd(&t[c0.z], z2);
        atomicAdd(&t[c0.w], z3);
        atomicAdd(&t[c1.x], z4);
        atomicAdd(&t[c1.y], z5);
        atomicAdd(&t[c1.z], z6);
        atomicAdd(&t[c1.w], z7);
    } else {
        for (int i = base; i < e; ++i) atomicAdd(&t[col[i]], z[row[i]]);
    }
}

// between hops: x' = dis*t ; z_next = dis*x' = t/(deg+1) ; t = z_next (self loop)
__global__ void k_post(const float* __restrict__ deg, float* __restrict__ z,
                       float* __restrict__ t, int n) {
    int i = blockIdx.x * blockDim.x + threadIdx.x;
    if (i < n) {
        float v = t[i] / (deg[i] + 1.0f);
        z[i] = v;
        t[i] = v;
    }
}

// segment sum/count over sorted batch vector, wave-uniform fast path
__global__ void k_reduce(const float* __restrict__ deg, const float* __restrict__ t,
                         const int* __restrict__ batch,
                         float* __restrict__ s, float* __restrict__ c, int n) {
    int i = blockIdx.x * blockDim.x + threadIdx.x;
    int lane = threadIdx.x & 63;
    float y = 0.0f;
    int g = -1;
    if (i < n) {
        y = rsqrtf(deg[i] + 1.0f) * t[i];  // final hop's output
        g = batch[i];
    }
    int g0 = __shfl(g, 0);
    if (__all(g == g0) && g0 >= 0) {
        float sum = y;
        #pragma unroll
        for (int off = 32; off; off >>= 1) sum += __shfl_down(sum, off);
        if (lane == 0) {
            atomicAdd(&s[g0], sum);
            atomicAdd(&c[g0], 64.0f);
        }
    } else if (g >= 0) {
        atomicAdd(&s[g], y);
        atomicAdd(&c[g], 1.0f);
    }
}

__global__ void k_final(const float* __restrict__ s, const float* __restrict__ c,
                        const float* __restrict__ b, float* __restrict__ out, int g) {
    int i = blockIdx.x * blockDim.x + threadIdx.x;
    if (i < g) out[i] = s[i] / fmaxf(c[i], 1.0f) + b[0];
}

extern "C" void kernel_launch(void* const* d_in, const int* in_sizes, int n_in,
                              void* d_out, int out_size, void* d_ws, size_t ws_size,
                              hipStream_t stream) {
    const float* x    = (const float*)d_in[0];   // [N,128]
    const float* W    = (const float*)d_in[1];   // [128,1]
    const float* b    = (const float*)d_in[2];   // [1]
    const int*   ei   = (const int*)d_in[3];     // [2,E]
    const int*   batch= (const int*)d_in[4];     // [N]
    float* out = (float*)d_out;                  // [G,1]

    const int N = in_sizes[0] / 128;
    const int E = in_sizes[3] / 2;
    const int G = out_size;

    const int* row = ei;        // edge_index[0]
    const int* col = ei + E;    // edge_index[1]

    // workspace layout (floats): deg[N] | s[G] | c[G] | z[N] | t[N]
    float* deg = (float*)d_ws;
    float* s   = deg + N;
    float* c   = s + G;
    float* z   = c + G;
    float* t   = z + N;

    // zero deg + per-graph accumulators in one shot (ws is poisoned every call)
    hipMemsetAsync(deg, 0, ((size_t)N + 2 * (size_t)G) * sizeof(float), stream);

    int nbN = (N + BLK - 1) / BLK;
    int nbE = (E + BLK * EPT - 1) / (BLK * EPT);

    // degree (atomic pass, 8 edges/thread)
    k_deg_edges<<<nbE, BLK, 0, stream>>>(col, deg, E);

    // project to scalar first (linearity), init hop state
    int nbY = (N + (BLK / 64) - 1) / (BLK / 64);
    k_y<<<nbY, BLK, 0, stream>>>(x, W, deg, z, t, N);

    // K = 3 hops
    k_edges<<<nbE, BLK, 0, stream>>>(row, col, z, t, E);
    k_post<<<nbN, BLK, 0, stream>>>(deg, z, t, N);
    k_edges<<<nbE, BLK, 0, stream>>>(row, col, z, t, E);
    k_post<<<nbN, BLK, 0, stream>>>(deg, z, t, N);
    k_edges<<<nbE, BLK, 0, stream>>>(row, col, z, t, E);

    // segment mean over sorted batch + bias
    k_reduce<<<nbN, BLK, 0, stream>>>(deg, t, batch, s, c, N);
    k_final<<<(G + BLK - 1) / BLK, BLK, 0, stream>>>(s, c, b, out, G);
}

// Round 3
// 235.604 us; speedup vs baseline: 2.0906x; 2.0906x over previous
//
#include <hip/hip_runtime.h>

// SGConv regression, commuted: out = mean_g( S^K (x @ W) + b )
// N=100000 nodes, E=1600000 edges, F=128, K=3 hops, G=512 graphs.
// Round 2: kill the 4 device-atomic passes (18.5 Gatomic/s hard ceiling).
// Build CSR-by-col deterministically (radix-style partition + scan, LDS-only
// atomics), then hops become pull-mode gathers with zero global atomics.

#define BLK 256
#define CH 2048            // edges per partition block (kernels A/B)
#define NBITS 8
#define BSZ 256            // nodes per bucket = 1<<NBITS

// ---------------- scan helpers ----------------
__device__ inline unsigned int wave_incl_scan(unsigned int v) {
    int lane = threadIdx.x & 63;
    #pragma unroll
    for (int off = 1; off < 64; off <<= 1) {
        unsigned int u = (unsigned int)__shfl_up((int)v, off);
        if (lane >= off) v += u;
    }
    return v;
}

// 256-thread block exclusive scan; wsum4 is LDS[4]; total returned to all.
__device__ inline unsigned int block_excl_scan256(unsigned int v,
                                                  unsigned int* wsum4,
                                                  unsigned int& total) {
    int tid = threadIdx.x, lane = tid & 63, w = tid >> 6;
    unsigned int inc = wave_incl_scan(v);
    __syncthreads();                 // protect wsum4 reuse
    if (lane == 63) wsum4[w] = inc;
    __syncthreads();
    unsigned int wbase = 0;
    #pragma unroll
    for (int k = 0; k < 4; ++k) if (k < w) wbase += wsum4[k];
    total = wsum4[0] + wsum4[1] + wsum4[2] + wsum4[3];
    return wbase + inc - v;          // exclusive prefix
}

// ---------------- kernel A: per-partition bucket histogram ----------------
// HT[v * NB + b] = #edges in partition b with (col>>NBITS)==v
__global__ void kA_hist(const int* __restrict__ col, int E, int NB, int NBUK,
                        unsigned int* __restrict__ HT) {
    __shared__ unsigned int lh[512];
    int b = blockIdx.x;
    for (int j = threadIdx.x; j < NBUK; j += BLK) lh[j] = 0;
    __syncthreads();
    int s0 = b * CH, s1 = min(E, s0 + CH);
    for (int i = s0 + threadIdx.x; i < s1; i += BLK)
        atomicAdd(&lh[((unsigned int)col[i]) >> NBITS], 1u);
    __syncthreads();
    for (int j = threadIdx.x; j < NBUK; j += BLK)
        HT[(size_t)j * NB + b] = lh[j];
}

// ---------------- scan over HT (length L), 3 kernels ----------------
__global__ void kS1(const unsigned int* __restrict__ HT, int L,
                    unsigned int* __restrict__ partial) {
    __shared__ unsigned int wsum[4];
    int i = blockIdx.x * BLK + threadIdx.x;
    unsigned int v = (i < L) ? HT[i] : 0u;
    unsigned int tot;
    block_excl_scan256(v, wsum, tot);
    if (threadIdx.x == 0) partial[blockIdx.x] = tot;
}

__global__ void kS2(unsigned int* __restrict__ partial, int NP) {
    __shared__ unsigned int wsum[4];
    int tid = threadIdx.x;
    int cpt = (NP + BLK - 1) / BLK;
    int a0 = tid * cpt, a1 = min(NP, a0 + cpt);
    unsigned int s = 0;
    for (int i = a0; i < a1; ++i) s += partial[i];
    unsigned int tot;
    unsigned int base = block_excl_scan256(s, wsum, tot);
    unsigned int run = base;
    for (int i = a0; i < a1; ++i) {
        unsigned int t = partial[i];
        partial[i] = run;
        run += t;
    }
}

__global__ void kS3(unsigned int* __restrict__ HT, int L,
                    const unsigned int* __restrict__ partial) {
    __shared__ unsigned int wsum[4];
    int i = blockIdx.x * BLK + threadIdx.x;
    unsigned int v = (i < L) ? HT[i] : 0u;
    unsigned int tot;
    unsigned int ex = block_excl_scan256(v, wsum, tot);
    if (i < L) HT[i] = ex + partial[blockIdx.x];
}

// ---------------- kernel B: scatter edges into bucket-grouped order --------
__global__ void kB_scatter(const int* __restrict__ row, const int* __restrict__ col,
                           int E, int NB, int NBUK,
                           const unsigned int* __restrict__ scanned,
                           int2* __restrict__ pairs) {
    __shared__ unsigned int lbase[512];
    __shared__ unsigned int lcnt[512];
    int b = blockIdx.x;
    for (int j = threadIdx.x; j < NBUK; j += BLK) {
        lbase[j] = scanned[(size_t)j * NB + b];
        lcnt[j] = 0;
    }
    __syncthreads();
    int s0 = b * CH, s1 = min(E, s0 + CH);
    for (int i = s0 + threadIdx.x; i < s1; i += BLK) {
        int c = col[i];
        int r = row[i];
        unsigned int bin = ((unsigned int)c) >> NBITS;
        unsigned int rk = atomicAdd(&lcnt[bin], 1u);     // LDS atomic (fast)
        pairs[lbase[bin] + rk] = make_int2(r, c);
    }
}

// ---------------- kernel C: per-bucket CSR finalize (one block/bucket) -----
__global__ void kC_build(const int2* __restrict__ pairs, int E, int NB, int NBUK,
                         int N, const unsigned int* __restrict__ scanned,
                         int* __restrict__ csr, int* __restrict__ off) {
    __shared__ unsigned int lh[BSZ];
    __shared__ unsigned int lo[BSZ];
    __shared__ unsigned int wsum[4];
    int v = blockIdx.x;
    unsigned int S0 = scanned[(size_t)v * NB];
    unsigned int S1 = (v + 1 < NBUK) ? scanned[(size_t)(v + 1) * NB] : (unsigned int)E;
    int tid = threadIdx.x;
    lh[tid] = 0;
    __syncthreads();
    for (unsigned int i = S0 + tid; i < S1; i += BLK)
        atomicAdd(&lh[pairs[i].y & (BSZ - 1)], 1u);
    __syncthreads();
    unsigned int tot;
    unsigned int ex = block_excl_scan256(lh[tid], wsum, tot);
    lo[tid] = ex;
    int node = (v << NBITS) + tid;
    if (node < N) off[node] = (int)(S0 + ex);
    if (v == NBUK - 1 && tid == 0) off[N] = E;
    __syncthreads();
    lh[tid] = 0;                      // reuse as rank counters
    __syncthreads();
    for (unsigned int i = S0 + tid; i < S1; i += BLK) {
        int2 p = pairs[i];
        unsigned int l = (unsigned int)p.y & (BSZ - 1);
        unsigned int rk = atomicAdd(&lh[l], 1u);
        csr[S0 + lo[l] + rk] = p.x;
    }
}

// ---------------- projection: z[v] = rsqrt(deg+1) * (x[v,:]·W) -------------
__global__ void k_y(const float* __restrict__ x, const float* __restrict__ W,
                    const int* __restrict__ off, float* __restrict__ z, int n) {
    int wave = blockIdx.x * (BLK / 64) + (threadIdx.x >> 6);
    int lane = threadIdx.x & 63;
    if (wave >= n) return;
    const float2* xr = (const float2*)(x + (size_t)wave * 128);
    float2 xv = xr[lane];
    float2 wv = ((const float2*)W)[lane];
    float s = xv.x * wv.x + xv.y * wv.y;
    #pragma unroll
    for (int o = 32; o; o >>= 1) s += __shfl_down(s, o);
    if (lane == 0) {
        float degp1 = (float)(off[wave + 1] - off[wave] + 1);
        z[wave] = rsqrtf(degp1) * s;
    }
}

// ---------------- pull-mode hop: zout = dis^2|dis * (z[v] + sum z[nbrs]) ---
template <bool FINAL>
__global__ void k_gather(const int* __restrict__ off, const int* __restrict__ csr,
                         const float* __restrict__ zin, float* __restrict__ zout,
                         int n) {
    int v = blockIdx.x * BLK + threadIdx.x;
    if (v >= n) return;
    int o0 = off[v], o1 = off[v + 1];
    float s = zin[v];                 // self loop term
    for (int j = o0; j < o1; ++j) s += zin[csr[j]];
    float degp1 = (float)(o1 - o0 + 1);
    zout[v] = FINAL ? s * rsqrtf(degp1) : s / degp1;
}

// ---------------- segment mean over sorted batch ----------------
__global__ void k_reduce(const float* __restrict__ y, const int* __restrict__ batch,
                         float* __restrict__ s, float* __restrict__ c, int n) {
    int i = blockIdx.x * blockDim.x + threadIdx.x;
    int lane = threadIdx.x & 63;
    float yv = 0.0f;
    int g = -1;
    if (i < n) {
        yv = y[i];
        g = batch[i];
    }
    int g0 = __shfl(g, 0);
    if (__all(g == g0) && g0 >= 0) {
        float sum = yv;
        #pragma unroll
        for (int o = 32; o; o >>= 1) sum += __shfl_down(sum, o);
        if (lane == 0) {
            atomicAdd(&s[g0], sum);
            atomicAdd(&c[g0], 64.0f);
        }
    } else if (g >= 0) {
        atomicAdd(&s[g], yv);
        atomicAdd(&c[g], 1.0f);
    }
}

__global__ void k_final(const float* __restrict__ s, const float* __restrict__ c,
                        const float* __restrict__ b, float* __restrict__ out, int g) {
    int i = blockIdx.x * blockDim.x + threadIdx.x;
    if (i < g) out[i] = s[i] / fmaxf(c[i], 1.0f) + b[0];
}

extern "C" void kernel_launch(void* const* d_in, const int* in_sizes, int n_in,
                              void* d_out, int out_size, void* d_ws, size_t ws_size,
                              hipStream_t stream) {
    const float* x     = (const float*)d_in[0];  // [N,128]
    const float* W     = (const float*)d_in[1];  // [128,1]
    const float* b     = (const float*)d_in[2];  // [1]
    const int*   ei    = (const int*)d_in[3];    // [2,E]
    const int*   batch = (const int*)d_in[4];    // [N]
    float* out = (float*)d_out;                  // [G,1]

    const int N = in_sizes[0] / 128;
    const int E = in_sizes[3] / 2;
    const int G = out_size;

    const int* row = ei;
    const int* col = ei + E;

    const int NBUK = (N + BSZ - 1) / BSZ;        // 391
    const int NB   = (E + CH - 1) / CH;          // 782
    const int L    = NBUK * NB;                  // ~306K
    const int NP   = (L + BLK - 1) / BLK;        // ~1195

    // workspace layout
    char* w = (char*)d_ws;
    int2*          pairs   = (int2*)w;                 w += (size_t)E * 8;
    int*           csr     = (int*)w;                  w += (size_t)E * 4;
    int*           off     = (int*)w;                  w += (size_t)(N + 1) * 4;
    unsigned int*  scanned = (unsigned int*)w;         w += (size_t)L * 4;
    unsigned int*  partial = (unsigned int*)w;         w += (size_t)NP * 4;
    float*         z0      = (float*)w;                w += (size_t)N * 4;
    float*         z1      = (float*)w;                w += (size_t)N * 4;
    float*         s       = (float*)w;                w += (size_t)G * 4;
    float*         c       = (float*)w;                // + G*4

    hipMemsetAsync(s, 0, 2 * (size_t)G * sizeof(float), stream);

    // CSR build (deterministic, no global atomics)
    kA_hist<<<NB, BLK, 0, stream>>>(col, E, NB, NBUK, scanned);
    kS1<<<NP, BLK, 0, stream>>>(scanned, L, partial);
    kS2<<<1, BLK, 0, stream>>>(partial, NP);
    kS3<<<NP, BLK, 0, stream>>>(scanned, L, partial);
    kB_scatter<<<NB, BLK, 0, stream>>>(row, col, E, NB, NBUK, scanned, pairs);
    kC_build<<<NBUK, BLK, 0, stream>>>(pairs, E, NB, NBUK, N, scanned, csr, off);

    // projection to scalar (linearity: S^3(xW) = (S^3 x)W)
    int nbY = (N + (BLK / 64) - 1) / (BLK / 64);
    k_y<<<nbY, BLK, 0, stream>>>(x, W, off, z0, N);

    // 3 pull-mode hops
    int nbN = (N + BLK - 1) / BLK;
    k_gather<false><<<nbN, BLK, 0, stream>>>(off, csr, z0, z1, N);
    k_gather<false><<<nbN, BLK, 0, stream>>>(off, csr, z1, z0, N);
    k_gather<true ><<<nbN, BLK, 0, stream>>>(off, csr, z0, z1, N);

    // segment mean + bias
    k_reduce<<<nbN, BLK, 0, stream>>>(z1, batch, s, c, N);
    k_final<<<(G + BLK - 1) / BLK, BLK, 0, stream>>>(s, c, b, out, G);
}

// Round 4
// 228.937 us; speedup vs baseline: 2.1515x; 1.0291x over previous
//
#include <hip/hip_runtime.h>

// SGConv regression, commuted: out = mean_g( S^K (x @ W) + b )
// N=100000, E=1600000, F=128, K=3, G=512.
// Round 3: edge-parallel hops with LDS accumulators (no CSR finalize, no
// per-node serial loops). Packed 1-int edges (row | local_col<<20).

#define BLK 256
#define CH 2048            // edges per partition block (kernels A/B)
#define NBITS 7
#define BSZ 128            // nodes per bucket = 1<<NBITS
#define ROWMASK 0xFFFFFu   // 20 bits for row (N < 2^17)

// ---------------- scan helpers ----------------
__device__ inline unsigned int wave_incl_scan(unsigned int v) {
    int lane = threadIdx.x & 63;
    #pragma unroll
    for (int off = 1; off < 64; off <<= 1) {
        unsigned int u = (unsigned int)__shfl_up((int)v, off);
        if (lane >= off) v += u;
    }
    return v;
}

__device__ inline unsigned int block_excl_scan256(unsigned int v,
                                                  unsigned int* wsum4,
                                                  unsigned int& total) {
    int tid = threadIdx.x, lane = tid & 63, w = tid >> 6;
    unsigned int inc = wave_incl_scan(v);
    __syncthreads();
    if (lane == 63) wsum4[w] = inc;
    __syncthreads();
    unsigned int wbase = 0;
    #pragma unroll
    for (int k = 0; k < 4; ++k) if (k < w) wbase += wsum4[k];
    total = wsum4[0] + wsum4[1] + wsum4[2] + wsum4[3];
    return wbase + inc - v;
}

// ---------------- kernel A: per-partition bucket histogram ----------------
__global__ void kA_hist(const int* __restrict__ col, int E, int NB, int NBUK,
                        unsigned int* __restrict__ HT) {
    __shared__ unsigned int lh[1024];
    int b = blockIdx.x;
    for (int j = threadIdx.x; j < NBUK; j += BLK) lh[j] = 0;
    __syncthreads();
    int s0 = b * CH, s1 = min(E, s0 + CH);
    for (int i = s0 + threadIdx.x; i < s1; i += BLK)
        atomicAdd(&lh[((unsigned int)col[i]) >> NBITS], 1u);
    __syncthreads();
    for (int j = threadIdx.x; j < NBUK; j += BLK)
        HT[(size_t)j * NB + b] = lh[j];
}

// ---------------- scan over HT (length L), 3 kernels ----------------
__global__ void kS1(const unsigned int* __restrict__ HT, int L,
                    unsigned int* __restrict__ partial) {
    __shared__ unsigned int wsum[4];
    int i = blockIdx.x * BLK + threadIdx.x;
    unsigned int v = (i < L) ? HT[i] : 0u;
    unsigned int tot;
    block_excl_scan256(v, wsum, tot);
    if (threadIdx.x == 0) partial[blockIdx.x] = tot;
}

__global__ void kS2(unsigned int* __restrict__ partial, int NP) {
    __shared__ unsigned int wsum[4];
    int tid = threadIdx.x;
    int cpt = (NP + BLK - 1) / BLK;
    int a0 = tid * cpt, a1 = min(NP, a0 + cpt);
    unsigned int s = 0;
    for (int i = a0; i < a1; ++i) s += partial[i];
    unsigned int tot;
    unsigned int base = block_excl_scan256(s, wsum, tot);
    unsigned int run = base;
    for (int i = a0; i < a1; ++i) {
        unsigned int t = partial[i];
        partial[i] = run;
        run += t;
    }
}

__global__ void kS3(unsigned int* __restrict__ HT, int L,
                    const unsigned int* __restrict__ partial) {
    __shared__ unsigned int wsum[4];
    int i = blockIdx.x * BLK + threadIdx.x;
    unsigned int v = (i < L) ? HT[i] : 0u;
    unsigned int tot;
    unsigned int ex = block_excl_scan256(v, wsum, tot);
    if (i < L) HT[i] = ex + partial[blockIdx.x];
}

// ------- kernel B: scatter packed edges (row | local<<20) by bucket -------
__global__ void kB_scatter(const int* __restrict__ row, const int* __restrict__ col,
                           int E, int NB, int NBUK,
                           const unsigned int* __restrict__ scanned,
                           unsigned int* __restrict__ packed) {
    __shared__ unsigned int lbase[1024];
    __shared__ unsigned int lcnt[1024];
    int b = blockIdx.x;
    for (int j = threadIdx.x; j < NBUK; j += BLK) {
        lbase[j] = scanned[(size_t)j * NB + b];
        lcnt[j] = 0;
    }
    __syncthreads();
    int s0 = b * CH, s1 = min(E, s0 + CH);
    for (int i = s0 + threadIdx.x; i < s1; i += BLK) {
        unsigned int c = (unsigned int)col[i];
        unsigned int r = (unsigned int)row[i];
        unsigned int bin = c >> NBITS;
        unsigned int rk = atomicAdd(&lcnt[bin], 1u);      // LDS atomic
        packed[lbase[bin] + rk] = r | ((c & (BSZ - 1)) << 20);
    }
}

// ---------------- kernel D: per-node degree via bucket histogram ----------
__global__ void kD_deg(const unsigned int* __restrict__ packed,
                       const unsigned int* __restrict__ scanned,
                       int E, int NB, int NBUK, int N,
                       float* __restrict__ degp1) {
    __shared__ unsigned int cnt[BSZ];
    int v = blockIdx.x;
    unsigned int S0 = scanned[(size_t)v * NB];
    unsigned int S1 = (v + 1 < NBUK) ? scanned[(size_t)(v + 1) * NB] : (unsigned int)E;
    int tid = threadIdx.x;
    if (tid < BSZ) cnt[tid] = 0;
    __syncthreads();
    unsigned int i = S0 + tid;
    for (; i + 3u * BLK < S1; i += 4u * BLK) {
        unsigned int p0 = packed[i];
        unsigned int p1 = packed[i + BLK];
        unsigned int p2 = packed[i + 2u * BLK];
        unsigned int p3 = packed[i + 3u * BLK];
        atomicAdd(&cnt[p0 >> 20], 1u);
        atomicAdd(&cnt[p1 >> 20], 1u);
        atomicAdd(&cnt[p2 >> 20], 1u);
        atomicAdd(&cnt[p3 >> 20], 1u);
    }
    for (; i < S1; i += BLK) atomicAdd(&cnt[packed[i] >> 20], 1u);
    __syncthreads();
    if (tid < BSZ) {
        int node = (v << NBITS) + tid;
        if (node < N) degp1[node] = (float)(cnt[tid] + 1u);
    }
}

// ---------------- projection: z[v] = rsqrt(deg+1) * (x[v,:]·W) ------------
__global__ void k_y(const float* __restrict__ x, const float* __restrict__ W,
                    const float* __restrict__ degp1, float* __restrict__ z, int n) {
    int wave = blockIdx.x * (BLK / 64) + (threadIdx.x >> 6);
    int lane = threadIdx.x & 63;
    if (wave >= n) return;
    const float2* xr = (const float2*)(x + (size_t)wave * 128);
    float2 xv = xr[lane];
    float2 wv = ((const float2*)W)[lane];
    float s = xv.x * wv.x + xv.y * wv.y;
    #pragma unroll
    for (int o = 32; o; o >>= 1) s += __shfl_down(s, o);
    if (lane == 0) z[wave] = rsqrtf(degp1[wave]) * s;
}

// -------- edge-parallel hop: one block per bucket, LDS accumulation -------
template <bool FINAL>
__global__ void k_hop(const unsigned int* __restrict__ packed,
                      const unsigned int* __restrict__ scanned,
                      int E, int NB, int NBUK, int N,
                      const float* __restrict__ degp1,
                      const float* __restrict__ zin,
                      float* __restrict__ zout) {
    __shared__ float acc[BSZ];
    int v = blockIdx.x;
    unsigned int S0 = scanned[(size_t)v * NB];
    unsigned int S1 = (v + 1 < NBUK) ? scanned[(size_t)(v + 1) * NB] : (unsigned int)E;
    int tid = threadIdx.x;
    if (tid < BSZ) acc[tid] = 0.0f;
    __syncthreads();
    unsigned int i = S0 + tid;
    for (; i + 3u * BLK < S1; i += 4u * BLK) {
        unsigned int p0 = packed[i];
        unsigned int p1 = packed[i + BLK];
        unsigned int p2 = packed[i + 2u * BLK];
        unsigned int p3 = packed[i + 3u * BLK];
        float z0 = zin[p0 & ROWMASK];
        float z1 = zin[p1 & ROWMASK];
        float z2 = zin[p2 & ROWMASK];
        float z3 = zin[p3 & ROWMASK];
        atomicAdd(&acc[p0 >> 20], z0);
        atomicAdd(&acc[p1 >> 20], z1);
        atomicAdd(&acc[p2 >> 20], z2);
        atomicAdd(&acc[p3 >> 20], z3);
    }
    for (; i < S1; i += BLK) {
        unsigned int p = packed[i];
        atomicAdd(&acc[p >> 20], zin[p & ROWMASK]);
    }
    __syncthreads();
    if (tid < BSZ) {
        int node = (v << NBITS) + tid;
        if (node < N) {
            float s = zin[node] + acc[tid];
            float d = degp1[node];
            zout[node] = FINAL ? s * rsqrtf(d) : s / d;
        }
    }
}

// ---------------- segment mean over sorted batch ----------------
__global__ void k_reduce(const float* __restrict__ y, const int* __restrict__ batch,
                         float* __restrict__ s, float* __restrict__ c, int n) {
    int i = blockIdx.x * blockDim.x + threadIdx.x;
    int lane = threadIdx.x & 63;
    float yv = 0.0f;
    int g = -1;
    if (i < n) {
        yv = y[i];
        g = batch[i];
    }
    int g0 = __shfl(g, 0);
    if (__all(g == g0) && g0 >= 0) {
        float sum = yv;
        #pragma unroll
        for (int o = 32; o; o >>= 1) sum += __shfl_down(sum, o);
        if (lane == 0) {
            atomicAdd(&s[g0], sum);
            atomicAdd(&c[g0], 64.0f);
        }
    } else if (g >= 0) {
        atomicAdd(&s[g], yv);
        atomicAdd(&c[g], 1.0f);
    }
}

__global__ void k_final(const float* __restrict__ s, const float* __restrict__ c,
                        const float* __restrict__ b, float* __restrict__ out, int g) {
    int i = blockIdx.x * blockDim.x + threadIdx.x;
    if (i < g) out[i] = s[i] / fmaxf(c[i], 1.0f) + b[0];
}

extern "C" void kernel_launch(void* const* d_in, const int* in_sizes, int n_in,
                              void* d_out, int out_size, void* d_ws, size_t ws_size,
                              hipStream_t stream) {
    const float* x     = (const float*)d_in[0];  // [N,128]
    const float* W     = (const float*)d_in[1];  // [128,1]
    const float* b     = (const float*)d_in[2];  // [1]
    const int*   ei    = (const int*)d_in[3];    // [2,E]
    const int*   batch = (const int*)d_in[4];    // [N]
    float* out = (float*)d_out;                  // [G,1]

    const int N = in_sizes[0] / 128;
    const int E = in_sizes[3] / 2;
    const int G = out_size;

    const int* row = ei;
    const int* col = ei + E;

    const int NBUK = (N + BSZ - 1) / BSZ;        // 782
    const int NB   = (E + CH - 1) / CH;          // 782
    const int L    = NBUK * NB;                  // ~611K
    const int NP   = (L + BLK - 1) / BLK;        // ~2389

    // workspace layout
    char* w = (char*)d_ws;
    unsigned int* packed  = (unsigned int*)w;  w += (size_t)E * 4;
    unsigned int* scanned = (unsigned int*)w;  w += (size_t)L * 4;
    unsigned int* partial = (unsigned int*)w;  w += (size_t)NP * 4;
    float*        degp1   = (float*)w;         w += (size_t)N * 4;
    float*        z0      = (float*)w;         w += (size_t)N * 4;
    float*        z1      = (float*)w;         w += (size_t)N * 4;
    float*        s       = (float*)w;         w += (size_t)G * 4;
    float*        c       = (float*)w;         // + G*4

    hipMemsetAsync(s, 0, 2 * (size_t)G * sizeof(float), stream);

    // bucket-grouped packed edge list (deterministic, LDS atomics only)
    kA_hist<<<NB, BLK, 0, stream>>>(col, E, NB, NBUK, scanned);
    kS1<<<NP, BLK, 0, stream>>>(scanned, L, partial);
    kS2<<<1, BLK, 0, stream>>>(partial, NP);
    kS3<<<NP, BLK, 0, stream>>>(scanned, L, partial);
    kB_scatter<<<NB, BLK, 0, stream>>>(row, col, E, NB, NBUK, scanned, packed);
    kD_deg<<<NBUK, BLK, 0, stream>>>(packed, scanned, E, NB, NBUK, N, degp1);

    // projection to scalar (linearity: S^3(xW) = (S^3 x)W)
    int nbY = (N + (BLK / 64) - 1) / (BLK / 64);
    k_y<<<nbY, BLK, 0, stream>>>(x, W, degp1, z0, N);

    // 3 edge-parallel hops
    k_hop<false><<<NBUK, BLK, 0, stream>>>(packed, scanned, E, NB, NBUK, N, degp1, z0, z1);
    k_hop<false><<<NBUK, BLK, 0, stream>>>(packed, scanned, E, NB, NBUK, N, degp1, z1, z0);
    k_hop<true ><<<NBUK, BLK, 0, stream>>>(packed, scanned, E, NB, NBUK, N, degp1, z0, z1);

    // segment mean + bias
    int nbN = (N + BLK - 1) / BLK;
    k_reduce<<<nbN, BLK, 0, stream>>>(z1, batch, s, c, N);
    k_final<<<(G + BLK - 1) / BLK, BLK, 0, stream>>>(s, c, b, out, G);
}